// Round 2
// 414.655 us; speedup vs baseline: 1.0216x; 1.0216x over previous
//
#include <hip/hip_runtime.h>

// SNN LIF scan: T=1024, B=32, N=2048. EXACT sequential-in-T (spikes are
// binary -> trajectory must be bit-exact -> no T-parallelization, R2).
// R5: one thread per TWO adjacent neurons, float2 loads AND float2 spike
// stores (halves vmem op count vs scalar; 2-way per-thread ILP).
// R6/R7: kernel is ~95% vmcnt-stall (423us = 990 cy/timestep vs ~40 issue
// cycles). Occupancy is problem-capped at 2 waves/CU, so raise memory-level
// parallelism per wave instead:
//   - U 16 -> 32: 32 outstanding 8B loads = 16 KB/wave (32 KB/CU) in
//     flight, above the Little's-law knee for ~6.3 TB/s at ~1.5k cy latency.
//   - nontemporal loads+stores: 537 MB is touched exactly once; nt keeps the
//     stream from churning L2/L3 and shortens store-ack latency, which gates
//     load retirement through in-order vmcnt.
//   - R7 fix: __builtin_nontemporal_* rejects HIP_vector_type (float2 is a
//     struct) -> use clang ext_vector_type(2) for all vmem traffic.
// d_out layout: spikes[T*B*N] ++ v_final[B*N] ++ i_final[B*N].

#define TT 1024
#define BN 65536           // B*N
#define BN2 (BN / 2)       // stride per timestep in vec2 units
#define U  32              // vec2 batch per pipeline phase (2 phases)

typedef float v2f __attribute__((ext_vector_type(2)));

__global__ __launch_bounds__(128, 1) void snn_lif_kernel(
    const float* __restrict__ xf,
    float* __restrict__ outf)
{
    const int idx = blockIdx.x * 128 + threadIdx.x;       // 0..BN2-1
    const v2f* __restrict__ xp = (const v2f*)xf + idx;
    v2f* __restrict__ sp = (v2f*)outf + idx;

    float v0 = 0.0f, v1 = 0.0f;
    float i0 = 0.0f, i1 = 0.0f;

    const float c_mem = 0.1f;   // fp32(DT*TAU_MEM_INV)
    const float c_syn = 0.8f;   // fp32(1 - DT*TAU_SYN_INV)

    // One LIF step for one neuron. Exact ref op sequence; _rn intrinsics
    // forbid FMA contraction (spike decisions are binary -- must match the
    // fp32 reference bit-exactly; this is load-bearing, do not touch).
    auto step = [&](float& v, float& i, float xin) -> float {
        float dv    = __fmul_rn(c_mem, __fadd_rn(__fsub_rn(0.0f, v), i));
        float v_dec = __fadd_rn(v, dv);
        float i_dec = __fmul_rn(i, c_syn);
        bool fired  = (v_dec > 1.0f);
        v = fired ? 0.0f : v_dec;
        i = __fadd_rn(i_dec, xin);
        return fired ? 1.0f : 0.0f;
    };

    v2f xa[U], xb[U];

    // Prologue: batch A in flight.
    #pragma unroll
    for (int k = 0; k < U; ++k)
        xa[k] = __builtin_nontemporal_load(&xp[(size_t)k * BN2]);

    #pragma unroll 1
    for (int t0 = 0; t0 < TT; t0 += 2 * U) {
        // Issue batch B before consuming batch A.
        #pragma unroll
        for (int k = 0; k < U; ++k)
            xb[k] = __builtin_nontemporal_load(&xp[(size_t)(t0 + U + k) * BN2]);

        #pragma unroll
        for (int k = 0; k < U; ++k) {
            v2f z;
            z.x = step(v0, i0, xa[k].x);
            z.y = step(v1, i1, xa[k].y);
            __builtin_nontemporal_store(z, &sp[(size_t)(t0 + k) * BN2]);
        }

        // Refill batch A for the next outer iteration (uniform branch).
        if (t0 + 2 * U < TT) {
            #pragma unroll
            for (int k = 0; k < U; ++k)
                xa[k] = __builtin_nontemporal_load(&xp[(size_t)(t0 + 2 * U + k) * BN2]);
        }

        #pragma unroll
        for (int k = 0; k < U; ++k) {
            v2f z;
            z.x = step(v0, i0, xb[k].x);
            z.y = step(v1, i1, xb[k].y);
            __builtin_nontemporal_store(z, &sp[(size_t)(t0 + U + k) * BN2]);
        }
    }

    // Final state (vec2 contiguous in both v and i regions).
    v2f* vf = (v2f*)(outf + (size_t)TT * BN) + idx;
    v2f* iff = (v2f*)(outf + (size_t)TT * BN + BN) + idx;
    v2f vfin; vfin.x = v0; vfin.y = v1;
    v2f ifin; ifin.x = i0; ifin.y = i1;
    *vf = vfin;
    *iff = ifin;
}

extern "C" void kernel_launch(void* const* d_in, const int* in_sizes, int n_in,
                              void* d_out, int out_size, void* d_ws, size_t ws_size,
                              hipStream_t stream) {
    const float* x = (const float*)d_in[0];
    float* out = (float*)d_out;
    // BN2 = 32768 threads -> 256 blocks of 128 -> 1 block/CU, 2 waves/CU.
    snn_lif_kernel<<<BN2 / 128, 128, 0, stream>>>(x, out);
}